// Round 2
// baseline (757.733 us; speedup 1.0000x reference)
//
#include <hip/hip_runtime.h>
#include <stdint.h>

typedef unsigned long long ull;

#define K_ANCH   8192
#define NCLS     91
#define NCC      90
#define B_SZ     8
#define CAP      1024          // per-(b,c) candidate capacity (mean ~330, 37 sigma margin)
#define PRE_NMS  1000
#define MAXDET   100
#define SCORE_TH 0.05f
#define IOU_TH   0.5f
#define BBOX_CLIP 4.1351665565490723f   // float(log(1000/16))

__device__ __forceinline__ float wave_max64(float v) {
  #pragma unroll
  for (int off = 32; off > 0; off >>= 1) v = fmaxf(v, __shfl_xor(v, off, 64));
  return v;
}
__device__ __forceinline__ float wave_sum64(float v) {
  #pragma unroll
  for (int off = 32; off > 0; off >>= 1) v += __shfl_xor(v, off, 64);
  return v;
}

// Decode + clip, formulas mirror reference op-for-op; block fma contraction so
// rounding matches a non-fused reference as closely as possible.
__device__ __forceinline__ float4 decode_clip(float4 e, float4 a, float imh, float imw) {
#pragma clang fp contract(off)
  float dy = e.x / 10.0f;
  float dx = e.y / 10.0f;
  float dh = fminf(e.z / 5.0f, BBOX_CLIP);
  float dw = fminf(e.w / 5.0f, BBOX_CLIP);
  float ah = a.z - a.x;
  float aw = a.w - a.y;
  float ayc = a.x + 0.5f * ah;
  float axc = a.y + 0.5f * aw;
  float yc = dy * ah + ayc;
  float xc = dx * aw + axc;
  float h = expf(dh) * ah;
  float w = expf(dw) * aw;
  float y1 = yc - 0.5f * h, x1 = xc - 0.5f * w;
  float y2 = yc + 0.5f * h, x2 = xc + 0.5f * w;
  y1 = fminf(fmaxf(y1, 0.0f), imh);
  x1 = fminf(fmaxf(x1, 0.0f), imw);
  y2 = fminf(fmaxf(y2, 0.0f), imh);
  x2 = fminf(fmaxf(x2, 0.0f), imw);
  return make_float4(y1, x1, y2, x2);
}

__device__ __forceinline__ bool iou_gt(float by1, float bx1, float by2, float bx2, float ba,
                                       float jy1, float jx1, float jy2, float jx2, float ja) {
#pragma clang fp contract(off)
  float iy1 = fmaxf(by1, jy1);
  float ix1 = fmaxf(bx1, jx1);
  float iy2 = fminf(by2, jy2);
  float ix2 = fminf(bx2, jx2);
  float inter = fmaxf(iy2 - iy1, 0.0f) * fmaxf(ix2 - ix1, 0.0f);
  float uni = ba + ja - inter;
  float iou = inter / (uni > 0.0f ? uni : 1.0f);
  return iou > IOU_TH;
}

// --- K1: softmax + threshold + decode + bucket append. One wave per (b,k) row.
__global__ __launch_bounds__(256) void k1_collect(
    const float* __restrict__ raw_boxes, const float* __restrict__ raw_scores,
    const float* __restrict__ anchors, const float* __restrict__ image_shape,
    int* __restrict__ counters, ull* __restrict__ cand_key, float4* __restrict__ cand_box)
{
  int wave = (int)((blockIdx.x * (unsigned)blockDim.x + threadIdx.x) >> 6);
  int lane = threadIdx.x & 63;
  if (wave >= B_SZ * K_ANCH) return;
  int b = wave >> 13;          // / 8192
  int k = wave & (K_ANCH - 1);

  const float* srow = raw_scores + (size_t)wave * NCLS;
  float s0 = srow[lane];                                   // classes 0..63
  bool has1 = (lane < NCLS - 64);                          // classes 64..90
  float s1 = has1 ? srow[lane + 64] : -INFINITY;

  float m = wave_max64(fmaxf(s0, s1));
  float e0 = expf(s0 - m);
  float e1 = has1 ? expf(s1 - m) : 0.0f;
  float denom = wave_sum64(e0 + e1);

  float4 a = ((const float4*)anchors)[wave];
  float imh = image_shape[b * 2 + 0];
  float imw = image_shape[b * 2 + 1];

  const float4* brow = ((const float4*)raw_boxes) + (size_t)wave * NCLS;

  // candidate from c0 = lane (skip background class 0)
  float p0 = e0 / denom;
  if (lane >= 1 && p0 > SCORE_TH) {
    float4 box = decode_clip(brow[lane], a, imh, imw);
    int bc = b * NCC + (lane - 1);
    int slot = atomicAdd(&counters[bc], 1);
    if (slot < CAP) {
      ull key = ((ull)__float_as_uint(p0) << 32) | (uint32_t)(K_ANCH - 1 - k);
      cand_key[(size_t)bc * CAP + slot] = key;
      cand_box[(size_t)bc * CAP + slot] = box;
    }
  }
  // candidate from c1 = lane + 64
  if (has1) {
    float p1 = e1 / denom;
    if (p1 > SCORE_TH) {
      int c = lane + 64;
      float4 box = decode_clip(brow[c], a, imh, imw);
      int bc = b * NCC + (c - 1);
      int slot = atomicAdd(&counters[bc], 1);
      if (slot < CAP) {
        ull key = ((ull)__float_as_uint(p1) << 32) | (uint32_t)(K_ANCH - 1 - k);
        cand_key[(size_t)bc * CAP + slot] = key;
        cand_box[(size_t)bc * CAP + slot] = box;
      }
    }
  }
}

// --- K2: per-(b,c) sort + greedy NMS + compact first-100 valid. One block per (b,c).
__global__ __launch_bounds__(256) void k2_sort_nms(
    const int* __restrict__ counters, const ull* __restrict__ cand_key,
    const float4* __restrict__ cand_box, float* __restrict__ all_s, float4* __restrict__ all_b)
{
  __shared__ ull   skey[CAP];
  __shared__ int   sslot[CAP];
  __shared__ float sy1[PRE_NMS], sx1[PRE_NMS], sy2[PRE_NMS], sx2[PRE_NMS], sarea[PRE_NMS];
  __shared__ int   salive[PRE_NMS];

  int bc  = blockIdx.x;
  int tid = threadIdx.x;
  int n_load = min(counters[bc], CAP);
  size_t base = (size_t)bc * CAP;
  int outbase = bc * MAXDET;   // bc*100 == b*9000 + cm1*100

  // zero this (b,c)'s output region (ws is poisoned each launch)
  for (int i = tid; i < MAXDET; i += 256) {
    all_s[outbase + i] = 0.0f;
    all_b[outbase + i] = make_float4(0.f, 0.f, 0.f, 0.f);
  }
  for (int i = tid; i < CAP; i += 256) {
    if (i < n_load) { skey[i] = cand_key[base + i]; sslot[i] = i; }
    else            { skey[i] = 0ull;               sslot[i] = 0; }
  }
  __syncthreads();

  // bitonic sort, descending by key = (score_bits << 32) | (8191 - k)
  for (int size = 2; size <= CAP; size <<= 1) {
    for (int stride = size >> 1; stride > 0; stride >>= 1) {
      for (int i = tid; i < CAP; i += 256) {
        int j = i ^ stride;
        if (j > i) {
          ull ki = skey[i], kj = skey[j];
          bool desc = ((i & size) == 0);
          if (desc ? (ki < kj) : (ki > kj)) {
            skey[i] = kj; skey[j] = ki;
            int t = sslot[i]; sslot[i] = sslot[j]; sslot[j] = t;
          }
        }
      }
      __syncthreads();
    }
  }

  int n_use = min(n_load, PRE_NMS);
  for (int i = tid; i < n_use; i += 256) {
    float4 bx = cand_box[base + sslot[i]];
    sy1[i] = bx.x; sx1[i] = bx.y; sy2[i] = bx.z; sx2[i] = bx.w;
    {
#pragma clang fp contract(off)
      sarea[i] = (bx.z - bx.x) * (bx.w - bx.y);
    }
    salive[i] = 1;
  }
  __syncthreads();

  // greedy NMS: barrier only after a kept box's suppression sweep
  for (int i = 0; i < n_use; i++) {
    if (salive[i]) {              // uniform (same LDS address for all threads)
      float by1 = sy1[i], bx1 = sx1[i], by2 = sy2[i], bx2 = sx2[i], ba = sarea[i];
      for (int j = i + 1 + tid; j < n_use; j += 256) {
        if (salive[j] &&
            iou_gt(by1, bx1, by2, bx2, ba, sy1[j], sx1[j], sy2[j], sx2[j], sarea[j]))
          salive[j] = 0;
      }
      __syncthreads();
    }
  }
  __syncthreads();

  // wave 0: compact first 100 kept & valid (any coord > 0) entries, in sorted order
  if (tid < 64) {
    int lane = tid;
    int written = 0;
    for (int cbase = 0; cbase < n_use && written < MAXDET; cbase += 64) {
      int i = cbase + lane;
      bool v = false;
      float sc = 0.f, y1 = 0.f, x1 = 0.f, y2 = 0.f, x2 = 0.f;
      if (i < n_use && salive[i]) {
        y1 = sy1[i]; x1 = sx1[i]; y2 = sy2[i]; x2 = sx2[i];
        if (y1 > 0.f || x1 > 0.f || y2 > 0.f || x2 > 0.f) {
          v = true;
          sc = __uint_as_float((uint32_t)(skey[i] >> 32));
        }
      }
      ull mask = __ballot(v);
      int pos = written + __popcll(mask & ((1ull << lane) - 1ull));
      if (v && pos < MAXDET) {
        all_s[outbase + pos] = sc;
        all_b[outbase + pos] = make_float4(y1, x1, y2, x2);
      }
      written += __popcll(mask);
    }
  }
}

// --- K3: 90-way merge of sorted per-class lists -> final top-100 per batch. One wave per b.
__global__ __launch_bounds__(64) void k3_final(
    const float* __restrict__ all_s, const float4* __restrict__ all_b,
    float* __restrict__ out)
{
  int b = blockIdx.x;
  int lane = threadIdx.x;
  const float* S = all_s + (size_t)b * NCC * MAXDET;

  float* fin_b = out;                          // (B,100,4)
  float* fin_s = out + B_SZ * MAXDET * 4;      // (B,100)
  float* fin_c = fin_s + B_SZ * MAXDET;        // (B,100)
  float* numo  = fin_c + B_SZ * MAXDET;        // (B,)

  int c0 = lane;           // class-slice 0..63
  int c1 = lane + 64;      // class-slice 64..89 (valid lane < 26)
  int p0 = 0, p1 = 0;
  int cnt = 0;

  for (int step = 0; step < MAXDET; step++) {
    ull k0 = 0ull, k1 = 0ull;
    if (p0 < MAXDET) {
      int flat = c0 * MAXDET + p0;
      k0 = ((ull)__float_as_uint(S[flat]) << 32) | (uint32_t)(16383 - flat);
    }
    if (c1 < NCC && p1 < MAXDET) {
      int flat = c1 * MAXDET + p1;
      k1 = ((ull)__float_as_uint(S[flat]) << 32) | (uint32_t)(16383 - flat);
    }
    ull my = (k0 > k1) ? k0 : k1;
    ull g = my;
    #pragma unroll
    for (int off = 32; off > 0; off >>= 1) {
      ull o = __shfl_xor(g, off, 64);
      g = (o > g) ? o : g;
    }
    // advance the winning list (keys are unique)
    if (g == k0 && k0 != 0ull)      p0++;
    else if (g == k1 && k1 != 0ull) p1++;

    if (lane == 0) {
      int flat = 16383 - (int)(g & 0xFFFFFFFFull);
      int cc = flat / MAXDET;
      float sc = __uint_as_float((uint32_t)(g >> 32));
      fin_s[b * MAXDET + step] = sc;
      fin_c[b * MAXDET + step] = (float)(cc + 1);
      float4 bx = all_b[(size_t)b * NCC * MAXDET + flat];
      ((float4*)fin_b)[b * MAXDET + step] = bx;
      if (sc > -1.0f) cnt++;
    }
  }
  if (lane == 0) numo[b] = (float)cnt;
}

extern "C" void kernel_launch(void* const* d_in, const int* in_sizes, int n_in,
                              void* d_out, int out_size, void* d_ws, size_t ws_size,
                              hipStream_t stream) {
  const float* raw_boxes   = (const float*)d_in[0];
  const float* raw_scores  = (const float*)d_in[1];
  const float* anchors     = (const float*)d_in[2];
  const float* image_shape = (const float*)d_in[3];

  char* p = (char*)d_ws;
  auto alloc = [&](size_t bytes) {
    char* r = p;
    p += (bytes + 255) & ~(size_t)255;
    return r;
  };
  int*    counters = (int*)   alloc((size_t)B_SZ * NCC * sizeof(int));
  ull*    cand_key = (ull*)   alloc((size_t)B_SZ * NCC * CAP * sizeof(ull));
  float4* cand_box = (float4*)alloc((size_t)B_SZ * NCC * CAP * sizeof(float4));
  float*  all_s    = (float*) alloc((size_t)B_SZ * NCC * MAXDET * sizeof(float));
  float4* all_b    = (float4*)alloc((size_t)B_SZ * NCC * MAXDET * sizeof(float4));

  (void)hipMemsetAsync(counters, 0, (size_t)B_SZ * NCC * sizeof(int), stream);

  int rows = B_SZ * K_ANCH;             // 65536 waves, 4 per block
  k1_collect<<<rows / 4, 256, 0, stream>>>(raw_boxes, raw_scores, anchors, image_shape,
                                           counters, cand_key, cand_box);
  k2_sort_nms<<<B_SZ * NCC, 256, 0, stream>>>(counters, cand_key, cand_box, all_s, all_b);
  k3_final<<<B_SZ, 64, 0, stream>>>(all_s, all_b, (float*)d_out);
}

// Round 3
// 466.283 us; speedup vs baseline: 1.6250x; 1.6250x over previous
//
#include <hip/hip_runtime.h>
#include <stdint.h>

typedef unsigned long long ull;

#define K_ANCH   8192
#define NCLS     91
#define NCC      90
#define B_SZ     8
#define CAP      1024          // per-(b,c) candidate capacity = NSHARD * SCAP
#define NSHARD   8             // shards per bucket (by anchor range) to cut atomic depth
#define SCAP     128           // slots per shard (mean ~41, 13+ sigma margin)
#define CPAD     16            // ints per counter (64B line each -> no false sharing)
#define PRE_NMS  1000
#define MAXDET   100
#define SCORE_TH 0.05f
#define IOU_TH   0.5f
#define BBOX_CLIP 4.1351665565490723f   // float(log(1000/16))

__device__ __forceinline__ float wave_max64(float v) {
  #pragma unroll
  for (int off = 32; off > 0; off >>= 1) v = fmaxf(v, __shfl_xor(v, off, 64));
  return v;
}
__device__ __forceinline__ float wave_sum64(float v) {
  #pragma unroll
  for (int off = 32; off > 0; off >>= 1) v += __shfl_xor(v, off, 64);
  return v;
}

__device__ __forceinline__ float4 decode_clip(float4 e, float4 a, float imh, float imw) {
#pragma clang fp contract(off)
  float dy = e.x / 10.0f;
  float dx = e.y / 10.0f;
  float dh = fminf(e.z / 5.0f, BBOX_CLIP);
  float dw = fminf(e.w / 5.0f, BBOX_CLIP);
  float ah = a.z - a.x;
  float aw = a.w - a.y;
  float ayc = a.x + 0.5f * ah;
  float axc = a.y + 0.5f * aw;
  float yc = dy * ah + ayc;
  float xc = dx * aw + axc;
  float h = expf(dh) * ah;
  float w = expf(dw) * aw;
  float y1 = yc - 0.5f * h, x1 = xc - 0.5f * w;
  float y2 = yc + 0.5f * h, x2 = xc + 0.5f * w;
  y1 = fminf(fmaxf(y1, 0.0f), imh);
  x1 = fminf(fmaxf(x1, 0.0f), imw);
  y2 = fminf(fmaxf(y2, 0.0f), imh);
  x2 = fminf(fmaxf(x2, 0.0f), imw);
  return make_float4(y1, x1, y2, x2);
}

__device__ __forceinline__ bool iou_gt(float by1, float bx1, float by2, float bx2, float ba,
                                       float jy1, float jx1, float jy2, float jx2, float ja) {
#pragma clang fp contract(off)
  float iy1 = fmaxf(by1, jy1);
  float ix1 = fmaxf(bx1, jx1);
  float iy2 = fminf(by2, jy2);
  float ix2 = fminf(bx2, jx2);
  float inter = fmaxf(iy2 - iy1, 0.0f) * fmaxf(ix2 - ix1, 0.0f);
  float uni = ba + ja - inter;
  float iou = inter / (uni > 0.0f ? uni : 1.0f);
  return iou > IOU_TH;
}

// --- K1: softmax + threshold + decode + sharded bucket append. One wave per (b,k) row.
__global__ __launch_bounds__(256) void k1_collect(
    const float* __restrict__ raw_boxes, const float* __restrict__ raw_scores,
    const float* __restrict__ anchors, const float* __restrict__ image_shape,
    int* __restrict__ counters, ull* __restrict__ cand_key, float4* __restrict__ cand_box)
{
  int wave = (int)((blockIdx.x * (unsigned)blockDim.x + threadIdx.x) >> 6);
  int lane = threadIdx.x & 63;
  if (wave >= B_SZ * K_ANCH) return;
  int b = wave >> 13;          // / 8192
  int k = wave & (K_ANCH - 1);
  int shard = (k >> 10) & (NSHARD - 1);

  const float* srow = raw_scores + (size_t)wave * NCLS;
  float s0 = srow[lane];                                   // classes 0..63
  bool has1 = (lane < NCLS - 64);                          // classes 64..90
  float s1 = has1 ? srow[lane + 64] : -INFINITY;

  float m = wave_max64(fmaxf(s0, s1));
  float e0 = expf(s0 - m);
  float e1 = has1 ? expf(s1 - m) : 0.0f;
  float denom = wave_sum64(e0 + e1);

  float4 a = ((const float4*)anchors)[wave];
  float imh = image_shape[b * 2 + 0];
  float imw = image_shape[b * 2 + 1];

  const float4* brow = ((const float4*)raw_boxes) + (size_t)wave * NCLS;

  // candidate from c0 = lane (skip background class 0)
  float p0 = e0 / denom;
  if (lane >= 1 && p0 > SCORE_TH) {
    float4 box = decode_clip(brow[lane], a, imh, imw);
    int bc = b * NCC + (lane - 1);
    int slot = atomicAdd(&counters[((bc << 3) + shard) << 4], 1);
    if (slot < SCAP) {
      ull key = ((ull)__float_as_uint(p0) << 32) | (uint32_t)(K_ANCH - 1 - k);
      size_t idx = (size_t)bc * CAP + (shard << 7) + slot;
      cand_key[idx] = key;
      cand_box[idx] = box;
    }
  }
  // candidate from c1 = lane + 64
  if (has1) {
    float p1 = e1 / denom;
    if (p1 > SCORE_TH) {
      int c = lane + 64;
      float4 box = decode_clip(brow[c], a, imh, imw);
      int bc = b * NCC + (c - 1);
      int slot = atomicAdd(&counters[((bc << 3) + shard) << 4], 1);
      if (slot < SCAP) {
        ull key = ((ull)__float_as_uint(p1) << 32) | (uint32_t)(K_ANCH - 1 - k);
        size_t idx = (size_t)bc * CAP + (shard << 7) + slot;
        cand_key[idx] = key;
        cand_box[idx] = box;
      }
    }
  }
}

// --- K2: per-(b,c) sort + greedy NMS + compact first-100 valid. One block per (b,c).
__global__ __launch_bounds__(256) void k2_sort_nms(
    const int* __restrict__ counters, const ull* __restrict__ cand_key,
    const float4* __restrict__ cand_box, float* __restrict__ all_s, float4* __restrict__ all_b)
{
  __shared__ ull   skey[CAP];
  __shared__ int   sslot[CAP];
  __shared__ float sy1[PRE_NMS], sx1[PRE_NMS], sy2[PRE_NMS], sx2[PRE_NMS], sarea[PRE_NMS];
  __shared__ int   salive[PRE_NMS];

  int bc  = blockIdx.x;
  int tid = threadIdx.x;
  size_t base = (size_t)bc * CAP;
  int outbase = bc * MAXDET;   // bc*100 == b*9000 + cm1*100

  // zero this (b,c)'s output region (ws is poisoned each launch)
  for (int i = tid; i < MAXDET; i += 256) {
    all_s[outbase + i] = 0.0f;
    all_b[outbase + i] = make_float4(0.f, 0.f, 0.f, 0.f);
  }

  // gather shard segments back-to-back (order irrelevant: sort restores it)
  int n_load = 0;
  for (int s = 0; s < NSHARD; s++) {
    int ns = min(counters[((bc << 3) + s) << 4], SCAP);
    for (int i = tid; i < ns; i += 256) {
      skey[n_load + i]  = cand_key[base + (s << 7) + i];
      sslot[n_load + i] = (s << 7) + i;
    }
    n_load += ns;
  }
  for (int i = n_load + tid; i < CAP; i += 256) { skey[i] = 0ull; sslot[i] = 0; }
  __syncthreads();

  // bitonic sort, descending by key = (score_bits << 32) | (8191 - k)
  for (int size = 2; size <= CAP; size <<= 1) {
    for (int stride = size >> 1; stride > 0; stride >>= 1) {
      for (int i = tid; i < CAP; i += 256) {
        int j = i ^ stride;
        if (j > i) {
          ull ki = skey[i], kj = skey[j];
          bool desc = ((i & size) == 0);
          if (desc ? (ki < kj) : (ki > kj)) {
            skey[i] = kj; skey[j] = ki;
            int t = sslot[i]; sslot[i] = sslot[j]; sslot[j] = t;
          }
        }
      }
      __syncthreads();
    }
  }

  int n_use = min(n_load, PRE_NMS);
  for (int i = tid; i < n_use; i += 256) {
    float4 bx = cand_box[base + sslot[i]];
    sy1[i] = bx.x; sx1[i] = bx.y; sy2[i] = bx.z; sx2[i] = bx.w;
    {
#pragma clang fp contract(off)
      sarea[i] = (bx.z - bx.x) * (bx.w - bx.y);
    }
    salive[i] = 1;
  }
  __syncthreads();

  // greedy NMS: barrier only after a kept box's suppression sweep
  for (int i = 0; i < n_use; i++) {
    if (salive[i]) {              // uniform (same LDS address for all threads)
      float by1 = sy1[i], bx1 = sx1[i], by2 = sy2[i], bx2 = sx2[i], ba = sarea[i];
      for (int j = i + 1 + tid; j < n_use; j += 256) {
        if (salive[j] &&
            iou_gt(by1, bx1, by2, bx2, ba, sy1[j], sx1[j], sy2[j], sx2[j], sarea[j]))
          salive[j] = 0;
      }
      __syncthreads();
    }
  }
  __syncthreads();

  // wave 0: compact first 100 kept & valid (any coord > 0) entries, in sorted order
  if (tid < 64) {
    int lane = tid;
    int written = 0;
    for (int cbase = 0; cbase < n_use && written < MAXDET; cbase += 64) {
      int i = cbase + lane;
      bool v = false;
      float sc = 0.f, y1 = 0.f, x1 = 0.f, y2 = 0.f, x2 = 0.f;
      if (i < n_use && salive[i]) {
        y1 = sy1[i]; x1 = sx1[i]; y2 = sy2[i]; x2 = sx2[i];
        if (y1 > 0.f || x1 > 0.f || y2 > 0.f || x2 > 0.f) {
          v = true;
          sc = __uint_as_float((uint32_t)(skey[i] >> 32));
        }
      }
      ull mask = __ballot(v);
      int pos = written + __popcll(mask & ((1ull << lane) - 1ull));
      if (v && pos < MAXDET) {
        all_s[outbase + pos] = sc;
        all_b[outbase + pos] = make_float4(y1, x1, y2, x2);
      }
      written += __popcll(mask);
    }
  }
}

// --- K3: 90-way merge of sorted per-class lists -> final top-100 per batch. One wave per b.
__global__ __launch_bounds__(64) void k3_final(
    const float* __restrict__ all_s, const float4* __restrict__ all_b,
    float* __restrict__ out)
{
  int b = blockIdx.x;
  int lane = threadIdx.x;
  const float* S = all_s + (size_t)b * NCC * MAXDET;

  float* fin_b = out;                          // (B,100,4)
  float* fin_s = out + B_SZ * MAXDET * 4;      // (B,100)
  float* fin_c = fin_s + B_SZ * MAXDET;        // (B,100)
  float* numo  = fin_c + B_SZ * MAXDET;        // (B,)

  int c0 = lane;           // class-slice 0..63
  int c1 = lane + 64;      // class-slice 64..89 (valid lane < 26)
  int p0 = 0, p1 = 0;
  int cnt = 0;

  for (int step = 0; step < MAXDET; step++) {
    ull k0 = 0ull, k1 = 0ull;
    if (p0 < MAXDET) {
      int flat = c0 * MAXDET + p0;
      k0 = ((ull)__float_as_uint(S[flat]) << 32) | (uint32_t)(16383 - flat);
    }
    if (c1 < NCC && p1 < MAXDET) {
      int flat = c1 * MAXDET + p1;
      k1 = ((ull)__float_as_uint(S[flat]) << 32) | (uint32_t)(16383 - flat);
    }
    ull my = (k0 > k1) ? k0 : k1;
    ull g = my;
    #pragma unroll
    for (int off = 32; off > 0; off >>= 1) {
      ull o = __shfl_xor(g, off, 64);
      g = (o > g) ? o : g;
    }
    // advance the winning list (keys are unique)
    if (g == k0 && k0 != 0ull)      p0++;
    else if (g == k1 && k1 != 0ull) p1++;

    if (lane == 0) {
      int flat = 16383 - (int)(g & 0xFFFFFFFFull);
      int cc = flat / MAXDET;
      float sc = __uint_as_float((uint32_t)(g >> 32));
      fin_s[b * MAXDET + step] = sc;
      fin_c[b * MAXDET + step] = (float)(cc + 1);
      float4 bx = all_b[(size_t)b * NCC * MAXDET + flat];
      ((float4*)fin_b)[b * MAXDET + step] = bx;
      if (sc > -1.0f) cnt++;
    }
  }
  if (lane == 0) numo[b] = (float)cnt;
}

extern "C" void kernel_launch(void* const* d_in, const int* in_sizes, int n_in,
                              void* d_out, int out_size, void* d_ws, size_t ws_size,
                              hipStream_t stream) {
  const float* raw_boxes   = (const float*)d_in[0];
  const float* raw_scores  = (const float*)d_in[1];
  const float* anchors     = (const float*)d_in[2];
  const float* image_shape = (const float*)d_in[3];

  char* p = (char*)d_ws;
  auto alloc = [&](size_t bytes) {
    char* r = p;
    p += (bytes + 255) & ~(size_t)255;
    return r;
  };
  size_t counters_bytes = (size_t)B_SZ * NCC * NSHARD * CPAD * sizeof(int); // 368 KB
  int*    counters = (int*)   alloc(counters_bytes);
  ull*    cand_key = (ull*)   alloc((size_t)B_SZ * NCC * CAP * sizeof(ull));
  float4* cand_box = (float4*)alloc((size_t)B_SZ * NCC * CAP * sizeof(float4));
  float*  all_s    = (float*) alloc((size_t)B_SZ * NCC * MAXDET * sizeof(float));
  float4* all_b    = (float4*)alloc((size_t)B_SZ * NCC * MAXDET * sizeof(float4));

  (void)hipMemsetAsync(counters, 0, counters_bytes, stream);

  int rows = B_SZ * K_ANCH;             // 65536 waves, 4 per block
  k1_collect<<<rows / 4, 256, 0, stream>>>(raw_boxes, raw_scores, anchors, image_shape,
                                           counters, cand_key, cand_box);
  k2_sort_nms<<<B_SZ * NCC, 256, 0, stream>>>(counters, cand_key, cand_box, all_s, all_b);
  k3_final<<<B_SZ, 64, 0, stream>>>(all_s, all_b, (float*)d_out);
}

// Round 4
// 398.018 us; speedup vs baseline: 1.9038x; 1.1715x over previous
//
#include <hip/hip_runtime.h>
#include <stdint.h>

typedef unsigned long long ull;

#define K_ANCH   8192
#define NCLS     91
#define NCC      90
#define B_SZ     8
#define CAP      1024          // per-(b,c) candidate capacity = NSHARD * SCAP
#define NSHARD   8             // shards per bucket (by anchor range) to cut atomic depth
#define SCAP     128           // slots per shard (mean ~41, 13+ sigma margin)
#define PRE_NMS  1000
#define MAXDET   100
#define CHUNK    128           // NMS mask-build chunk rows
#define NWMAX    16            // 1024/64 suppression-mask words
#define SCORE_TH 0.05f
#define IOU_TH   0.5f
#define BBOX_CLIP 4.1351665565490723f   // float(log(1000/16))

__device__ __forceinline__ float wave_max64(float v) {
  #pragma unroll
  for (int off = 32; off > 0; off >>= 1) v = fmaxf(v, __shfl_xor(v, off, 64));
  return v;
}
__device__ __forceinline__ float wave_sum64(float v) {
  #pragma unroll
  for (int off = 32; off > 0; off >>= 1) v += __shfl_xor(v, off, 64);
  return v;
}

__device__ __forceinline__ float4 decode_clip(float4 e, float4 a, float imh, float imw) {
#pragma clang fp contract(off)
  float dy = e.x / 10.0f;
  float dx = e.y / 10.0f;
  float dh = fminf(e.z / 5.0f, BBOX_CLIP);
  float dw = fminf(e.w / 5.0f, BBOX_CLIP);
  float ah = a.z - a.x;
  float aw = a.w - a.y;
  float ayc = a.x + 0.5f * ah;
  float axc = a.y + 0.5f * aw;
  float yc = dy * ah + ayc;
  float xc = dx * aw + axc;
  float h = expf(dh) * ah;
  float w = expf(dw) * aw;
  float y1 = yc - 0.5f * h, x1 = xc - 0.5f * w;
  float y2 = yc + 0.5f * h, x2 = xc + 0.5f * w;
  y1 = fminf(fmaxf(y1, 0.0f), imh);
  x1 = fminf(fmaxf(x1, 0.0f), imw);
  y2 = fminf(fmaxf(y2, 0.0f), imh);
  x2 = fminf(fmaxf(x2, 0.0f), imw);
  return make_float4(y1, x1, y2, x2);
}

__device__ __forceinline__ bool iou_gt(float4 bi, float ai, float4 bj, float aj) {
#pragma clang fp contract(off)
  float iy1 = fmaxf(bi.x, bj.x);
  float ix1 = fmaxf(bi.y, bj.y);
  float iy2 = fminf(bi.z, bj.z);
  float ix2 = fminf(bi.w, bj.w);
  float inter = fmaxf(iy2 - iy1, 0.0f) * fmaxf(ix2 - ix1, 0.0f);
  float uni = ai + aj - inter;
  float iou = inter / (uni > 0.0f ? uni : 1.0f);
  return iou > IOU_TH;
}

// --- K1: softmax + threshold + decode + sharded bucket append. One wave per (b,k) row.
__global__ __launch_bounds__(256) void k1_collect(
    const float* __restrict__ raw_boxes, const float* __restrict__ raw_scores,
    const float* __restrict__ anchors, const float* __restrict__ image_shape,
    int* __restrict__ counters, ull* __restrict__ cand_key, float4* __restrict__ cand_box)
{
  int wave = (int)((blockIdx.x * (unsigned)blockDim.x + threadIdx.x) >> 6);
  int lane = threadIdx.x & 63;
  if (wave >= B_SZ * K_ANCH) return;
  int b = wave >> 13;          // / 8192
  int k = wave & (K_ANCH - 1);
  int shard = (k >> 10) & (NSHARD - 1);

  const float* srow = raw_scores + (size_t)wave * NCLS;
  float s0 = srow[lane];                                   // classes 0..63
  bool has1 = (lane < NCLS - 64);                          // classes 64..90
  float s1 = has1 ? srow[lane + 64] : -INFINITY;

  float m = wave_max64(fmaxf(s0, s1));
  float e0 = expf(s0 - m);
  float e1 = has1 ? expf(s1 - m) : 0.0f;
  float denom = wave_sum64(e0 + e1);

  float4 a = ((const float4*)anchors)[wave];
  float imh = image_shape[b * 2 + 0];
  float imw = image_shape[b * 2 + 1];

  const float4* brow = ((const float4*)raw_boxes) + (size_t)wave * NCLS;

  // candidate from c0 = lane (skip background class 0)
  float p0 = e0 / denom;
  if (lane >= 1 && p0 > SCORE_TH) {
    float4 box = decode_clip(brow[lane], a, imh, imw);
    int bc = b * NCC + (lane - 1);
    int slot = atomicAdd(&counters[((bc << 3) + shard) << 4], 1);
    if (slot < SCAP) {
      ull key = ((ull)__float_as_uint(p0) << 32) | (uint32_t)(K_ANCH - 1 - k);
      size_t idx = (size_t)bc * CAP + (shard << 7) + slot;
      cand_key[idx] = key;
      cand_box[idx] = box;
    }
  }
  // candidate from c1 = lane + 64
  if (has1) {
    float p1 = e1 / denom;
    if (p1 > SCORE_TH) {
      int c = lane + 64;
      float4 box = decode_clip(brow[c], a, imh, imw);
      int bc = b * NCC + (c - 1);
      int slot = atomicAdd(&counters[((bc << 3) + shard) << 4], 1);
      if (slot < SCAP) {
        ull key = ((ull)__float_as_uint(p1) << 32) | (uint32_t)(K_ANCH - 1 - k);
        size_t idx = (size_t)bc * CAP + (shard << 7) + slot;
        cand_key[idx] = key;
        cand_box[idx] = box;
      }
    }
  }
}

// --- K2: per-(b,c) sort + mask-NMS + early-exit output. One block per (b,c).
__global__ __launch_bounds__(256) void k2_sort_nms(
    const int* __restrict__ counters, const ull* __restrict__ cand_key,
    const float4* __restrict__ cand_box, float* __restrict__ all_s, float4* __restrict__ all_b)
{
  __shared__ ull    skey[CAP];            //  8 KB
  __shared__ int    sslot[CAP];           //  4 KB
  __shared__ float4 sbox[PRE_NMS];        // 16 KB
  __shared__ float  sarea[PRE_NMS];       //  4 KB
  __shared__ ull    smask[CHUNK][NWMAX];  // 16 KB
  __shared__ int    s_done;

  int bc  = blockIdx.x;
  int tid = threadIdx.x;
  size_t base = (size_t)bc * CAP;
  int outbase = bc * MAXDET;   // bc*100 == b*9000 + cm1*100

  // zero this (b,c)'s output region (ws is poisoned each launch)
  for (int i = tid; i < MAXDET; i += 256) {
    all_s[outbase + i] = 0.0f;
    all_b[outbase + i] = make_float4(0.f, 0.f, 0.f, 0.f);
  }

  // gather shard segments back-to-back (order irrelevant: sort restores it)
  int n_load = 0;
  for (int s = 0; s < NSHARD; s++) {
    int ns = min(counters[((bc << 3) + s) << 4], SCAP);
    for (int i = tid; i < ns; i += 256) {
      skey[n_load + i]  = cand_key[base + (s << 7) + i];
      sslot[n_load + i] = (s << 7) + i;
    }
    n_load += ns;
  }
  int n2 = 256;
  while (n2 < n_load) n2 <<= 1;           // <= 1024
  for (int i = n_load + tid; i < n2; i += 256) { skey[i] = 0ull; sslot[i] = 0; }
  if (tid == 0) s_done = 0;
  __syncthreads();

  // bitonic sort over n2 elements, descending by key = (score_bits<<32)|(8191-k)
  for (int size = 2; size <= n2; size <<= 1) {
    for (int stride = size >> 1; stride > 0; stride >>= 1) {
      for (int i = tid; i < n2; i += 256) {
        int j = i ^ stride;
        if (j > i) {
          ull ki = skey[i], kj = skey[j];
          bool desc = ((i & size) == 0);
          if (desc ? (ki < kj) : (ki > kj)) {
            skey[i] = kj; skey[j] = ki;
            int t = sslot[i]; sslot[i] = sslot[j]; sslot[j] = t;
          }
        }
      }
      __syncthreads();
    }
  }

  int n_use = min(n_load, PRE_NMS);
  int nwords = (n_use + 63) >> 6;
  for (int i = tid; i < n_use; i += 256) {
    float4 bx = cand_box[base + sslot[i]];
    sbox[i] = bx;
    {
#pragma clang fp contract(off)
      sarea[i] = (bx.z - bx.x) * (bx.w - bx.y);
    }
  }

  // chunked mask NMS with early exit at 100 written detections
  ull rem = 0;        // wave0 lane l (<16) holds removed-word l; persists across chunks
  int written = 0;
  for (int c0 = 0; c0 < n_use; c0 += CHUNK) {
    __syncthreads();               // prev scan done / box-load visible
    if (s_done) break;             // uniform
    int nrows = min(CHUNK, n_use - c0);

    // build suppression-bit rows [c0, c0+nrows) x nwords, all 256 threads
    for (int p = tid; p < nrows * NWMAX; p += 256) {
      int w = p & (NWMAX - 1);
      int j0 = w << 6;
      if (j0 >= n_use) continue;                 // word never read (lane guard in scan)
      int r = c0 + (p >> 4);
      float4 br = sbox[r];
      float  ar = sarea[r];
      int j1 = min(j0 + 64, n_use);
      int js = max(j0, r + 1);
      ull mrow = 0;
      for (int j = js; j < j1; j++) {
        if (iou_gt(br, ar, sbox[j], sarea[j])) mrow |= 1ull << (j - j0);
      }
      smask[p >> 4][w] = mrow;
    }
    __syncthreads();               // build visible to wave 0

    if (tid < 64) {
      int lane = tid;
      for (int i = c0; i < c0 + nrows; i++) {
        int w = i >> 6, bit = i & 63;
        ull rw = __shfl(rem, w, 64);
        if (((rw >> bit) & 1ull) == 0) {         // alive
          // absorb this row's suppression mask (kept rows suppress later rows)
          if (lane < nwords) rem |= smask[i - c0][lane];
          // output if valid (any coord > 0)
          int valid = 0;
          float4 bx;
          float sc = 0.f;
          if (lane == 0) {
            bx = sbox[i];
            valid = (bx.x > 0.f || bx.y > 0.f || bx.z > 0.f || bx.w > 0.f) ? 1 : 0;
            sc = __uint_as_float((uint32_t)(skey[i] >> 32));
          }
          valid = __shfl(valid, 0, 64);
          if (valid) {
            if (lane == 0) {
              all_s[outbase + written] = sc;
              all_b[outbase + written] = bx;
            }
            written++;
            if (written == MAXDET) {
              if (lane == 0) s_done = 1;
              break;
            }
          }
        }
      }
    }
  }
}

// --- K3: 90-way merge of sorted per-class lists -> final top-100 per batch. One wave per b.
__global__ __launch_bounds__(64) void k3_final(
    const float* __restrict__ all_s, const float4* __restrict__ all_b,
    float* __restrict__ out)
{
  int b = blockIdx.x;
  int lane = threadIdx.x;
  const float* S = all_s + (size_t)b * NCC * MAXDET;

  float* fin_b = out;                          // (B,100,4)
  float* fin_s = out + B_SZ * MAXDET * 4;      // (B,100)
  float* fin_c = fin_s + B_SZ * MAXDET;        // (B,100)
  float* numo  = fin_c + B_SZ * MAXDET;        // (B,)

  int c0 = lane;           // class-slice 0..63
  int c1 = lane + 64;      // class-slice 64..89 (valid lane < 26)
  int p0 = 0, p1 = 0;
  int cnt = 0;

  for (int step = 0; step < MAXDET; step++) {
    ull k0 = 0ull, k1 = 0ull;
    if (p0 < MAXDET) {
      int flat = c0 * MAXDET + p0;
      k0 = ((ull)__float_as_uint(S[flat]) << 32) | (uint32_t)(16383 - flat);
    }
    if (c1 < NCC && p1 < MAXDET) {
      int flat = c1 * MAXDET + p1;
      k1 = ((ull)__float_as_uint(S[flat]) << 32) | (uint32_t)(16383 - flat);
    }
    ull my = (k0 > k1) ? k0 : k1;
    ull g = my;
    #pragma unroll
    for (int off = 32; off > 0; off >>= 1) {
      ull o = __shfl_xor(g, off, 64);
      g = (o > g) ? o : g;
    }
    // advance the winning list (keys are unique)
    if (g == k0 && k0 != 0ull)      p0++;
    else if (g == k1 && k1 != 0ull) p1++;

    if (lane == 0) {
      int flat = 16383 - (int)(g & 0xFFFFFFFFull);
      int cc = flat / MAXDET;
      float sc = __uint_as_float((uint32_t)(g >> 32));
      fin_s[b * MAXDET + step] = sc;
      fin_c[b * MAXDET + step] = (float)(cc + 1);
      float4 bx = all_b[(size_t)b * NCC * MAXDET + flat];
      ((float4*)fin_b)[b * MAXDET + step] = bx;
      if (sc > -1.0f) cnt++;
    }
  }
  if (lane == 0) numo[b] = (float)cnt;
}

extern "C" void kernel_launch(void* const* d_in, const int* in_sizes, int n_in,
                              void* d_out, int out_size, void* d_ws, size_t ws_size,
                              hipStream_t stream) {
  const float* raw_boxes   = (const float*)d_in[0];
  const float* raw_scores  = (const float*)d_in[1];
  const float* anchors     = (const float*)d_in[2];
  const float* image_shape = (const float*)d_in[3];

  char* p = (char*)d_ws;
  auto alloc = [&](size_t bytes) {
    char* r = p;
    p += (bytes + 255) & ~(size_t)255;
    return r;
  };
  size_t counters_bytes = (size_t)B_SZ * NCC * NSHARD * 16 * sizeof(int); // 64B/counter
  int*    counters = (int*)   alloc(counters_bytes);
  ull*    cand_key = (ull*)   alloc((size_t)B_SZ * NCC * CAP * sizeof(ull));
  float4* cand_box = (float4*)alloc((size_t)B_SZ * NCC * CAP * sizeof(float4));
  float*  all_s    = (float*) alloc((size_t)B_SZ * NCC * MAXDET * sizeof(float));
  float4* all_b    = (float4*)alloc((size_t)B_SZ * NCC * MAXDET * sizeof(float4));

  (void)hipMemsetAsync(counters, 0, counters_bytes, stream);

  int rows = B_SZ * K_ANCH;             // 65536 waves, 4 per block
  k1_collect<<<rows / 4, 256, 0, stream>>>(raw_boxes, raw_scores, anchors, image_shape,
                                           counters, cand_key, cand_box);
  k2_sort_nms<<<B_SZ * NCC, 256, 0, stream>>>(counters, cand_key, cand_box, all_s, all_b);
  k3_final<<<B_SZ, 64, 0, stream>>>(all_s, all_b, (float*)d_out);
}

// Round 5
// 310.185 us; speedup vs baseline: 2.4428x; 1.2832x over previous
//
#include <hip/hip_runtime.h>
#include <stdint.h>

typedef unsigned long long ull;

#define K_ANCH   8192
#define NCLS     91
#define NCC      90
#define B_SZ     8
#define CAP      1024          // per-(b,c) candidate capacity (mean ~330)
#define PRE_NMS  1000
#define MAXDET   100
#define CHUNK    128           // NMS mask-build chunk rows
#define NWMAX    16            // 1024/64 suppression-mask words
#define NBW      128           // bitmask words per (b,c) = 8192/64
#define SCORE_TH 0.05f
#define IOU_TH   0.5f
#define BBOX_CLIP 4.1351665565490723f   // float(log(1000/16))

__device__ __forceinline__ float wave_max64(float v) {
  #pragma unroll
  for (int off = 32; off > 0; off >>= 1) v = fmaxf(v, __shfl_xor(v, off, 64));
  return v;
}
__device__ __forceinline__ float wave_sum64(float v) {
  #pragma unroll
  for (int off = 32; off > 0; off >>= 1) v += __shfl_xor(v, off, 64);
  return v;
}

__device__ __forceinline__ float4 decode_clip(float4 e, float4 a, float imh, float imw) {
#pragma clang fp contract(off)
  float dy = e.x / 10.0f;
  float dx = e.y / 10.0f;
  float dh = fminf(e.z / 5.0f, BBOX_CLIP);
  float dw = fminf(e.w / 5.0f, BBOX_CLIP);
  float ah = a.z - a.x;
  float aw = a.w - a.y;
  float ayc = a.x + 0.5f * ah;
  float axc = a.y + 0.5f * aw;
  float yc = dy * ah + ayc;
  float xc = dx * aw + axc;
  float h = expf(dh) * ah;
  float w = expf(dw) * aw;
  float y1 = yc - 0.5f * h, x1 = xc - 0.5f * w;
  float y2 = yc + 0.5f * h, x2 = xc + 0.5f * w;
  y1 = fminf(fmaxf(y1, 0.0f), imh);
  x1 = fminf(fmaxf(x1, 0.0f), imw);
  y2 = fminf(fmaxf(y2, 0.0f), imh);
  x2 = fminf(fmaxf(x2, 0.0f), imw);
  return make_float4(y1, x1, y2, x2);
}

__device__ __forceinline__ bool iou_gt(float4 bi, float ai, float4 bj, float aj) {
#pragma clang fp contract(off)
  float iy1 = fmaxf(bi.x, bj.x);
  float ix1 = fmaxf(bi.y, bj.y);
  float iy2 = fminf(bi.z, bj.z);
  float ix2 = fminf(bi.w, bj.w);
  float inter = fmaxf(iy2 - iy1, 0.0f) * fmaxf(ix2 - ix1, 0.0f);
  float uni = ai + aj - inter;
  float iou = inter / (uni > 0.0f ? uni : 1.0f);
  return iou > IOU_TH;
}

// --- kT: softmax stats + transposed pass-bitmask. Block = 64 rows, 4 waves x 16 rows.
__global__ __launch_bounds__(256) void kT_softmax(
    const float* __restrict__ raw_scores,
    float2* __restrict__ stats, ull* __restrict__ bmask)
{
  __shared__ ull rowbits[64][2];
  int tid = threadIdx.x;
  int wv = tid >> 6, lane = tid & 63;
  int b = blockIdx.x >> 7;           // 128 blocks per batch
  int k0 = (blockIdx.x & 127) << 6;  // 64 rows per block
  for (int i = 0; i < 16; i++) {
    int rl = (wv << 4) + i;
    int row = b * K_ANCH + k0 + rl;
    const float* srow = raw_scores + (size_t)row * NCLS;
    float s0 = srow[lane];
    bool has1 = lane < (NCLS - 64);
    float s1 = has1 ? srow[64 + lane] : -INFINITY;
    float m = wave_max64(fmaxf(s0, s1));
    float e0 = expf(s0 - m);
    float e1 = has1 ? expf(s1 - m) : 0.0f;
    float denom = wave_sum64(e0 + e1);
    ull b0 = __ballot(lane >= 1 && (e0 / denom) > SCORE_TH);
    ull b1 = __ballot(has1 && (e1 / denom) > SCORE_TH);
    if (lane == 0) {
      stats[row] = make_float2(m, denom);
      rowbits[rl][0] = b0;
      rowbits[rl][1] = b1;
    }
  }
  __syncthreads();
  if (tid < NCC) {
    int c = tid + 1, w = c >> 6, bit = c & 63;
    ull out = 0;
    for (int r = 0; r < 64; r++)
      out |= ((rowbits[r][w] >> bit) & 1ull) << r;
    bmask[(size_t)(b * NCC + tid) * NBW + (k0 >> 6)] = out;
  }
}

// --- kN: per-(b,c) candidate extraction + sort + mask-NMS + early-exit output.
__global__ __launch_bounds__(256) void kN_nms(
    const float* __restrict__ raw_boxes, const float* __restrict__ raw_scores,
    const float* __restrict__ anchors, const float* __restrict__ image_shape,
    const float2* __restrict__ stats, const ull* __restrict__ bmask,
    float* __restrict__ all_s, float4* __restrict__ all_b)
{
  __shared__ ull    skey[CAP];              //  8 KB
  __shared__ float4 sbox[PRE_NMS];          // 16 KB
  __shared__ float  sarea[PRE_NMS];         //  4 KB
  __shared__ ull    smask[NWMAX][CHUNK + 1];// 16.5 KB (pad: scan-read conflict-free)
  __shared__ int    soff[NBW];
  __shared__ int    s_n;
  __shared__ int    s_done;

  int bc  = blockIdx.x;
  int tid = threadIdx.x;
  int b = bc / NCC;
  int c = bc - b * NCC + 1;
  int outbase = bc * MAXDET;

  // zero this (b,c)'s output region (ws is poisoned each launch)
  for (int i = tid; i < MAXDET; i += 256) {
    all_s[outbase + i] = 0.0f;
    all_b[outbase + i] = make_float4(0.f, 0.f, 0.f, 0.f);
  }

  // bitmask column -> counts
  ull w0 = 0;
  if (tid < NBW) {
    w0 = bmask[(size_t)bc * NBW + tid];
    soff[tid] = __popcll(w0);
  }
  if (tid == 0) s_done = 0;
  __syncthreads();
  if (tid == 0) {                       // serial exclusive scan over 128 words
    int acc = 0;
    for (int t = 0; t < NBW; t++) { int v = soff[t]; soff[t] = acc; acc += v; }
    s_n = acc;
  }
  __syncthreads();
  int n_load = min(s_n, CAP);

  // scatter k values (k-ascending, deterministic) as placeholders in skey
  if (tid < NBW) {
    int slot = soff[tid];
    ull m = w0;
    int kb = tid << 6;
    while (m) {
      int bit = __ffsll(m) - 1;
      m &= m - 1;
      if (slot < CAP) skey[slot] = (ull)(kb + bit);
      slot++;
    }
  }
  __syncthreads();

  // gather scores, build sort keys (bit-identical p = expf(s-m)/denom)
  size_t rowb = (size_t)b * K_ANCH;
  for (int i = tid; i < n_load; i += 256) {
    int k = (int)skey[i];
    size_t row = rowb + k;
    float s = raw_scores[row * NCLS + c];
    float2 md = stats[row];
    float p = expf(s - md.x) / md.y;
    skey[i] = ((ull)__float_as_uint(p) << 32) | (uint32_t)(K_ANCH - 1 - k);
  }
  int n2 = 256;
  while (n2 < n_load) n2 <<= 1;         // <= 1024
  for (int i = n_load + tid; i < n2; i += 256) skey[i] = 0ull;
  __syncthreads();

  // bitonic sort desc by key = (score_bits<<32)|(8191-k)
  for (int size = 2; size <= n2; size <<= 1) {
    for (int stride = size >> 1; stride > 0; stride >>= 1) {
      for (int i = tid; i < n2; i += 256) {
        int j = i ^ stride;
        if (j > i) {
          ull ki = skey[i], kj = skey[j];
          bool desc = ((i & size) == 0);
          if (desc ? (ki < kj) : (ki > kj)) { skey[i] = kj; skey[j] = ki; }
        }
      }
      __syncthreads();
    }
  }

  // decode boxes for sorted survivors
  int n_use = min(n_load, PRE_NMS);
  float imh = image_shape[b * 2 + 0];
  float imw = image_shape[b * 2 + 1];
  for (int i = tid; i < n_use; i += 256) {
    int k = K_ANCH - 1 - (int)(skey[i] & 0xFFFFFFFFull);
    size_t row = rowb + k;
    float4 e = ((const float4*)raw_boxes)[row * NCLS + c];
    float4 a = ((const float4*)anchors)[row];
    float4 box = decode_clip(e, a, imh, imw);
    sbox[i] = box;
    {
#pragma clang fp contract(off)
      sarea[i] = (box.z - box.x) * (box.w - box.y);
    }
  }

  // chunked mask NMS, early exit at 100 written
  int nwords = (n_use + 63) >> 6;
  ull rem = 0;        // wave0 lane l (<16) holds removed-word l
  int written = 0;
  for (int c0 = 0; c0 < n_use; c0 += CHUNK) {
    __syncthreads();               // prev scan done / box decode visible
    if (s_done) break;             // uniform
    int nrows = min(CHUNK, n_use - c0);

    // build: (w, rr) = (p>>7, p&127): wave-uniform w -> sbox[j] broadcast;
    // consecutive rr -> stride-16B conflict-free sbox[r] reads.
    for (int p = tid; p < (nwords << 7); p += 256) {
      int w  = p >> 7;
      int rr = p & (CHUNK - 1);
      if (rr >= nrows) continue;
      int r = c0 + rr;
      float4 br = sbox[r];
      float  ar = sarea[r];
      int j0 = w << 6;
      int j1 = min(j0 + 64, n_use);
      int js = max(j0, r + 1);
      ull mrow = 0;
      for (int j = js; j < j1; j++) {
        if (iou_gt(br, ar, sbox[j], sarea[j])) mrow |= 1ull << (j - j0);
      }
      smask[w][rr] = mrow;
    }
    __syncthreads();               // build visible to wave 0

    if (tid < 64) {
      int lane = tid;
      for (int i = c0; i < c0 + nrows; i++) {
        int w = i >> 6, bit = i & 63;
        ull rw = __shfl(rem, w, 64);
        if (((rw >> bit) & 1ull) == 0) {         // alive
          if (lane < nwords) rem |= smask[lane][i - c0];
          int valid = 0;
          float4 bx;
          float sc = 0.f;
          if (lane == 0) {
            bx = sbox[i];
            valid = (bx.x > 0.f || bx.y > 0.f || bx.z > 0.f || bx.w > 0.f) ? 1 : 0;
            sc = __uint_as_float((uint32_t)(skey[i] >> 32));
          }
          valid = __shfl(valid, 0, 64);
          if (valid) {
            if (lane == 0) {
              all_s[outbase + written] = sc;
              all_b[outbase + written] = bx;
            }
            written++;
            if (written == MAXDET) {
              if (lane == 0) s_done = 1;
              break;
            }
          }
        }
      }
    }
  }
}

// --- k3: 90-way merge of sorted per-class lists -> final top-100 per batch.
__global__ __launch_bounds__(256) void k3_final(
    const float* __restrict__ all_s, const float4* __restrict__ all_b,
    float* __restrict__ out)
{
  __shared__ float ss[NCC * MAXDET];   // 36 KB — all scores for this batch
  int b = blockIdx.x;
  int tid = threadIdx.x;
  const float* S = all_s + (size_t)b * NCC * MAXDET;
  for (int i = tid; i < NCC * MAXDET; i += 256) ss[i] = S[i];
  __syncthreads();
  if (tid >= 64) return;
  int lane = tid;

  float* fin_b = out;                          // (B,100,4)
  float* fin_s = out + B_SZ * MAXDET * 4;      // (B,100)
  float* fin_c = fin_s + B_SZ * MAXDET;        // (B,100)
  float* numo  = fin_c + B_SZ * MAXDET;        // (B,)

  int c0 = lane;           // class-slice 0..63
  int c1 = lane + 64;      // class-slice 64..89 (valid lane < 26)
  int p0 = 0, p1 = 0;
  // heads cached in registers; reload only on win
  ull k0 = ((ull)__float_as_uint(ss[c0 * MAXDET]) << 32) | (uint32_t)(16383 - c0 * MAXDET);
  ull k1 = (c1 < NCC)
         ? (((ull)__float_as_uint(ss[c1 * MAXDET]) << 32) | (uint32_t)(16383 - c1 * MAXDET))
         : 0ull;
  int cnt = 0;

  for (int step = 0; step < MAXDET; step++) {
    ull my = (k0 > k1) ? k0 : k1;
    ull g = my;
    #pragma unroll
    for (int off = 32; off > 0; off >>= 1) {
      ull o = __shfl_xor(g, off, 64);
      g = (o > g) ? o : g;
    }
    // advance the winning list (keys are unique)
    if (g == k0 && k0 != 0ull) {
      p0++;
      int flat = c0 * MAXDET + p0;
      k0 = (p0 < MAXDET)
         ? (((ull)__float_as_uint(ss[flat]) << 32) | (uint32_t)(16383 - flat))
         : 0ull;
    } else if (g == k1 && k1 != 0ull) {
      p1++;
      int flat = c1 * MAXDET + p1;
      k1 = (p1 < MAXDET)
         ? (((ull)__float_as_uint(ss[flat]) << 32) | (uint32_t)(16383 - flat))
         : 0ull;
    }

    if (lane == 0) {
      int flat = 16383 - (int)(g & 0xFFFFFFFFull);
      int cc = flat / MAXDET;
      float sc = __uint_as_float((uint32_t)(g >> 32));
      fin_s[b * MAXDET + step] = sc;
      fin_c[b * MAXDET + step] = (float)(cc + 1);
      float4 bx = all_b[(size_t)b * NCC * MAXDET + flat];
      ((float4*)fin_b)[b * MAXDET + step] = bx;
      if (sc > -1.0f) cnt++;
    }
  }
  if (lane == 0) numo[b] = (float)cnt;
}

extern "C" void kernel_launch(void* const* d_in, const int* in_sizes, int n_in,
                              void* d_out, int out_size, void* d_ws, size_t ws_size,
                              hipStream_t stream) {
  const float* raw_boxes   = (const float*)d_in[0];
  const float* raw_scores  = (const float*)d_in[1];
  const float* anchors     = (const float*)d_in[2];
  const float* image_shape = (const float*)d_in[3];

  char* p = (char*)d_ws;
  auto alloc = [&](size_t bytes) {
    char* r = p;
    p += (bytes + 255) & ~(size_t)255;
    return r;
  };
  float2* stats = (float2*)alloc((size_t)B_SZ * K_ANCH * sizeof(float2));       // 512 KB
  ull*    bmask = (ull*)   alloc((size_t)B_SZ * NCC * NBW * sizeof(ull));       // 720 KB
  float*  all_s = (float*) alloc((size_t)B_SZ * NCC * MAXDET * sizeof(float));  // 288 KB
  float4* all_b = (float4*)alloc((size_t)B_SZ * NCC * MAXDET * sizeof(float4)); // 1.15 MB

  kT_softmax<<<B_SZ * 128, 256, 0, stream>>>(raw_scores, stats, bmask);
  kN_nms<<<B_SZ * NCC, 256, 0, stream>>>(raw_boxes, raw_scores, anchors, image_shape,
                                         stats, bmask, all_s, all_b);
  k3_final<<<B_SZ, 256, 0, stream>>>(all_s, all_b, (float*)d_out);
}

// Round 6
// 303.227 us; speedup vs baseline: 2.4989x; 1.0229x over previous
//
#include <hip/hip_runtime.h>
#include <stdint.h>

typedef unsigned long long ull;

#define K_ANCH   8192
#define NCLS     91
#define NCC      90
#define B_SZ     8
#define CAP      1024          // per-(b,c) candidate capacity (mean ~330)
#define PRE_NMS  1000
#define MAXDET   100
#define CHUNK    64            // NMS mask-build chunk rows
#define NWMAX    16            // 1024/64 suppression-mask words
#define NBW      128           // bitmask words per (b,c) = 8192/64
#define SCORE_TH 0.05f
#define IOU_TH   0.5f
#define BBOX_CLIP 4.1351665565490723f   // float(log(1000/16))

__device__ __forceinline__ float wave_max64(float v) {
  #pragma unroll
  for (int off = 32; off > 0; off >>= 1) v = fmaxf(v, __shfl_xor(v, off, 64));
  return v;
}
__device__ __forceinline__ float wave_sum64(float v) {
  #pragma unroll
  for (int off = 32; off > 0; off >>= 1) v += __shfl_xor(v, off, 64);
  return v;
}

__device__ __forceinline__ float4 decode_clip(float4 e, float4 a, float imh, float imw) {
#pragma clang fp contract(off)
  float dy = e.x / 10.0f;
  float dx = e.y / 10.0f;
  float dh = fminf(e.z / 5.0f, BBOX_CLIP);
  float dw = fminf(e.w / 5.0f, BBOX_CLIP);
  float ah = a.z - a.x;
  float aw = a.w - a.y;
  float ayc = a.x + 0.5f * ah;
  float axc = a.y + 0.5f * aw;
  float yc = dy * ah + ayc;
  float xc = dx * aw + axc;
  float h = expf(dh) * ah;
  float w = expf(dw) * aw;
  float y1 = yc - 0.5f * h, x1 = xc - 0.5f * w;
  float y2 = yc + 0.5f * h, x2 = xc + 0.5f * w;
  y1 = fminf(fmaxf(y1, 0.0f), imh);
  x1 = fminf(fmaxf(x1, 0.0f), imw);
  y2 = fminf(fmaxf(y2, 0.0f), imh);
  x2 = fminf(fmaxf(x2, 0.0f), imw);
  return make_float4(y1, x1, y2, x2);
}

__device__ __forceinline__ bool iou_gt(float4 bi, float ai, float4 bj, float aj) {
#pragma clang fp contract(off)
  float iy1 = fmaxf(bi.x, bj.x);
  float ix1 = fmaxf(bi.y, bj.y);
  float iy2 = fminf(bi.z, bj.z);
  float ix2 = fminf(bi.w, bj.w);
  float inter = fmaxf(iy2 - iy1, 0.0f) * fmaxf(ix2 - ix1, 0.0f);
  float uni = ai + aj - inter;
  float iou = inter / (uni > 0.0f ? uni : 1.0f);
  return iou > IOU_TH;
}

// --- kT: softmax stats + transposed pass-bitmask. 1024 thr = 16 waves x 4 rows.
__global__ __launch_bounds__(1024) void kT_softmax(
    const float* __restrict__ raw_scores,
    float2* __restrict__ stats, ull* __restrict__ bmask)
{
  __shared__ ull rowbits[64][2];
  int tid = threadIdx.x;
  int wv = tid >> 6, lane = tid & 63;
  int b = blockIdx.x >> 7;           // 128 blocks per batch
  int k0 = (blockIdx.x & 127) << 6;  // 64 rows per block
  #pragma unroll
  for (int i = 0; i < 4; i++) {
    int rl = (wv << 2) + i;
    int row = b * K_ANCH + k0 + rl;
    const float* srow = raw_scores + (size_t)row * NCLS;
    float s0 = srow[lane];
    bool has1 = lane < (NCLS - 64);
    float s1 = has1 ? srow[64 + lane] : -INFINITY;
    float m = wave_max64(fmaxf(s0, s1));
    float e0 = expf(s0 - m);
    float e1 = has1 ? expf(s1 - m) : 0.0f;
    float denom = wave_sum64(e0 + e1);
    ull b0 = __ballot(lane >= 1 && (e0 / denom) > SCORE_TH);
    ull b1 = __ballot(has1 && (e1 / denom) > SCORE_TH);
    if (lane == 0) {
      stats[row] = make_float2(m, denom);
      rowbits[rl][0] = b0;
      rowbits[rl][1] = b1;
    }
  }
  __syncthreads();
  if (tid < NCC) {
    int c = tid + 1, w = c >> 6, bit = c & 63;
    ull out = 0;
    #pragma unroll
    for (int r = 0; r < 64; r++)
      out |= ((rowbits[r][w] >> bit) & 1ull) << r;
    bmask[(size_t)(b * NCC + tid) * NBW + (k0 >> 6)] = out;
  }
}

// --- kN: per-(b,c) candidate extraction + hybrid sort + mask-NMS + early-exit output.
__global__ __launch_bounds__(256) void kN_nms(
    const float* __restrict__ raw_boxes, const float* __restrict__ raw_scores,
    const float* __restrict__ anchors, const float* __restrict__ image_shape,
    const float2* __restrict__ stats, const ull* __restrict__ bmask,
    float* __restrict__ all_s, float4* __restrict__ all_b)
{
  __shared__ float4 sbox[PRE_NMS];          // 16 KB
  __shared__ float  sarea[PRE_NMS];         //  4 KB
  __shared__ float  sscore[PRE_NMS];        //  4 KB
  __shared__ ull    sbuf[1056];             // 8.45 KB: keys, then smask overlay
  __shared__ int    soff[NBW];
  __shared__ int    swtot[2];
  __shared__ int    s_n;
  __shared__ int    s_done;
#define SMASK(w, r) sbuf[(w) * (CHUNK + 1) + (r)]

  int bc  = blockIdx.x;
  int tid = threadIdx.x;
  int b = bc / NCC;
  int c = bc - b * NCC + 1;
  int outbase = bc * MAXDET;

  // zero this (b,c)'s output region (ws is poisoned each launch)
  for (int i = tid; i < MAXDET; i += 256) {
    all_s[outbase + i] = 0.0f;
    all_b[outbase + i] = make_float4(0.f, 0.f, 0.f, 0.f);
  }

  // bitmask column -> popcounts -> parallel exclusive scan (2 waves)
  ull w0 = 0;
  int cnt = 0;
  if (tid < NBW) { w0 = bmask[(size_t)bc * NBW + tid]; cnt = __popcll(w0); }
  int incl = cnt;
  if (tid < 128) {
    int lane = tid & 63;
    #pragma unroll
    for (int d = 1; d < 64; d <<= 1) {
      int o = __shfl_up(incl, d, 64);
      if (lane >= d) incl += o;
    }
    if (lane == 63) swtot[tid >> 6] = incl;
  }
  if (tid == 0) s_done = 0;
  __syncthreads();
  if (tid < 128) soff[tid] = incl - cnt + ((tid >= 64) ? swtot[0] : 0);
  if (tid == 0) s_n = swtot[0] + swtot[1];
  __syncthreads();
  int n_load = min(s_n, CAP);

  // scatter k values (k-ascending, deterministic) as placeholders
  if (tid < NBW) {
    int slot = soff[tid];
    ull m = w0;
    int kb = tid << 6;
    while (m) {
      int bit = __ffsll(m) - 1;
      m &= m - 1;
      if (slot < CAP) sbuf[slot] = (ull)(kb + bit);
      slot++;
    }
  }
  __syncthreads();

  // gather scores, build sort keys (bit-identical p = expf(s-m)/denom)
  size_t rowb = (size_t)b * K_ANCH;
  for (int i = tid; i < n_load; i += 256) {
    int k = (int)sbuf[i];
    size_t row = rowb + k;
    float s = raw_scores[row * NCLS + c];
    float2 md = stats[row];
    float p = expf(s - md.x) / md.y;
    sbuf[i] = ((ull)__float_as_uint(p) << 32) | (uint32_t)(K_ANCH - 1 - k);
  }
  int n2 = (n_load <= 512) ? 512 : 1024;
  for (int i = n_load + tid; i < n2; i += 256) sbuf[i] = 0ull;
  __syncthreads();

  // sort desc by key = (score_bits<<32)|(8191-k)
  if (n_load <= 512) {
    // hybrid bitonic: 2 keys/thread in regs; shfl for strides<=32, LDS for 64/128
    ull e0 = sbuf[tid], e1 = sbuf[tid + 256];
    for (int size = 2; size <= 512; size <<= 1) {
      if (size == 512 && e0 < e1) { ull t = e0; e0 = e1; e1 = t; }   // stride 256
      for (int s = ((size >> 1) > 128 ? 128 : (size >> 1)); s >= 64; s >>= 1) {
        __syncthreads();
        sbuf[tid] = e0; sbuf[tid + 256] = e1;
        __syncthreads();
        ull p0 = sbuf[tid ^ s];
        ull p1 = sbuf[(tid + 256) ^ s];
        bool t0 = (((tid & s) == 0) == ((tid & size) == 0));
        bool t1 = ((((tid + 256) & s) == 0) == (((tid + 256) & size) == 0));
        e0 = t0 ? (e0 > p0 ? e0 : p0) : (e0 < p0 ? e0 : p0);
        e1 = t1 ? (e1 > p1 ? e1 : p1) : (e1 < p1 ? e1 : p1);
      }
      int smax = ((size >> 1) < 32 ? (size >> 1) : 32);
      for (int s = smax; s >= 1; s >>= 1) {
        ull p0 = __shfl_xor(e0, s, 64);
        ull p1 = __shfl_xor(e1, s, 64);
        bool t0 = (((tid & s) == 0) == ((tid & size) == 0));
        bool t1 = ((((tid + 256) & s) == 0) == (((tid + 256) & size) == 0));
        e0 = t0 ? (e0 > p0 ? e0 : p0) : (e0 < p0 ? e0 : p0);
        e1 = t1 ? (e1 > p1 ? e1 : p1) : (e1 < p1 ? e1 : p1);
      }
    }
    __syncthreads();
    sbuf[tid] = e0;
    sbuf[tid + 256] = e1;
    __syncthreads();
  } else {
    // generic in-LDS bitonic over 1024 (statistically never taken; correctness net)
    for (int size = 2; size <= 1024; size <<= 1) {
      for (int stride = size >> 1; stride > 0; stride >>= 1) {
        for (int i = tid; i < 1024; i += 256) {
          int j = i ^ stride;
          if (j > i) {
            ull ki = sbuf[i], kj = sbuf[j];
            bool desc = ((i & size) == 0);
            if (desc ? (ki < kj) : (ki > kj)) { sbuf[i] = kj; sbuf[j] = ki; }
          }
        }
        __syncthreads();
      }
    }
  }

  // decode boxes for sorted survivors; extract scores (frees sbuf for smask)
  int n_use = min(n_load, PRE_NMS);
  float imh = image_shape[b * 2 + 0];
  float imw = image_shape[b * 2 + 1];
  for (int i = tid; i < n_use; i += 256) {
    ull key = sbuf[i];
    int k = K_ANCH - 1 - (int)(key & 0xFFFFFFFFull);
    size_t row = rowb + k;
    float4 e = ((const float4*)raw_boxes)[row * NCLS + c];
    float4 a = ((const float4*)anchors)[row];
    float4 box = decode_clip(e, a, imh, imw);
    sbox[i] = box;
    sscore[i] = __uint_as_float((uint32_t)(key >> 32));
    {
#pragma clang fp contract(off)
      sarea[i] = (box.z - box.x) * (box.w - box.y);
    }
  }

  // chunked mask NMS, early exit at 100 written. sbuf reused as smask.
  int nwords = (n_use + 63) >> 6;
  ull rem = 0;        // wave0 lane l (<16) holds removed-word l
  int written = 0;
  for (int c0 = 0; c0 < n_use; c0 += CHUNK) {
    __syncthreads();               // decode/prev-scan visible; sbuf safe to overwrite
    if (s_done) break;             // uniform
    int nrows = min(CHUNK, n_use - c0);

    // build: (w, rr) = (p>>6, p&63): wave-uniform w -> sbox[j] broadcast;
    // consecutive rr -> stride-16B conflict-free sbox[r] reads.
    for (int p = tid; p < (nwords << 6); p += 256) {
      int w  = p >> 6;
      int rr = p & (CHUNK - 1);
      if (rr >= nrows) continue;
      int r = c0 + rr;
      float4 br = sbox[r];
      float  ar = sarea[r];
      int j0 = w << 6;
      int j1 = min(j0 + 64, n_use);
      int js = max(j0, r + 1);
      ull mrow = 0;
      for (int j = js; j < j1; j++) {
        if (iou_gt(br, ar, sbox[j], sarea[j])) mrow |= 1ull << (j - j0);
      }
      SMASK(w, rr) = mrow;
    }
    __syncthreads();               // build visible to wave 0

    if (tid < 64) {
      int lane = tid;
      for (int i = c0; i < c0 + nrows; i++) {
        int w = i >> 6, bit = i & 63;
        ull rw = __shfl(rem, w, 64);
        if (((rw >> bit) & 1ull) == 0) {         // alive
          if (lane < nwords) rem |= SMASK(lane, i - c0);
          int valid = 0;
          float4 bx;
          float sc = 0.f;
          if (lane == 0) {
            bx = sbox[i];
            valid = (bx.x > 0.f || bx.y > 0.f || bx.z > 0.f || bx.w > 0.f) ? 1 : 0;
            sc = sscore[i];
          }
          valid = __shfl(valid, 0, 64);
          if (valid) {
            if (lane == 0) {
              all_s[outbase + written] = sc;
              all_b[outbase + written] = bx;
            }
            written++;
            if (written == MAXDET) {
              if (lane == 0) s_done = 1;
              break;
            }
          }
        }
      }
    }
  }
#undef SMASK
}

// --- k3: 90-way merge of sorted per-class lists -> final top-100 per batch.
__global__ __launch_bounds__(256) void k3_final(
    const float* __restrict__ all_s, const float4* __restrict__ all_b,
    float* __restrict__ out)
{
  __shared__ float ss[NCC * MAXDET];   // 36 KB — all scores for this batch
  int b = blockIdx.x;
  int tid = threadIdx.x;
  const float* S = all_s + (size_t)b * NCC * MAXDET;
  for (int i = tid; i < NCC * MAXDET; i += 256) ss[i] = S[i];
  __syncthreads();
  if (tid >= 64) return;
  int lane = tid;

  float* fin_b = out;                          // (B,100,4)
  float* fin_s = out + B_SZ * MAXDET * 4;      // (B,100)
  float* fin_c = fin_s + B_SZ * MAXDET;        // (B,100)
  float* numo  = fin_c + B_SZ * MAXDET;        // (B,)

  int c0 = lane;           // class-slice 0..63
  int c1 = lane + 64;      // class-slice 64..89 (valid lane < 26)
  int p0 = 0, p1 = 0;
  // heads + 1-deep prefetch: LDS reload latency stays off the critical path
  ull cur0 = ((ull)__float_as_uint(ss[c0 * MAXDET]) << 32) | (uint32_t)(16383 - c0 * MAXDET);
  ull nxt0 = ((ull)__float_as_uint(ss[c0 * MAXDET + 1]) << 32) | (uint32_t)(16383 - (c0 * MAXDET + 1));
  ull cur1 = 0ull, nxt1 = 0ull;
  if (c1 < NCC) {
    cur1 = ((ull)__float_as_uint(ss[c1 * MAXDET]) << 32) | (uint32_t)(16383 - c1 * MAXDET);
    nxt1 = ((ull)__float_as_uint(ss[c1 * MAXDET + 1]) << 32) | (uint32_t)(16383 - (c1 * MAXDET + 1));
  }
  int cnt = 0;

  for (int step = 0; step < MAXDET; step++) {
    ull my = (cur0 > cur1) ? cur0 : cur1;
    ull g = my;
    #pragma unroll
    for (int off = 32; off > 0; off >>= 1) {
      ull o = __shfl_xor(g, off, 64);
      g = (o > g) ? o : g;
    }
    // advance the winning list (keys are unique)
    if (cur0 != 0ull && g == cur0) {
      p0++;
      cur0 = nxt0;
      int f = c0 * MAXDET + p0 + 1;
      nxt0 = (p0 + 1 < MAXDET)
           ? (((ull)__float_as_uint(ss[f]) << 32) | (uint32_t)(16383 - f)) : 0ull;
    } else if (cur1 != 0ull && g == cur1) {
      p1++;
      cur1 = nxt1;
      int f = c1 * MAXDET + p1 + 1;
      nxt1 = (p1 + 1 < MAXDET)
           ? (((ull)__float_as_uint(ss[f]) << 32) | (uint32_t)(16383 - f)) : 0ull;
    }

    if (lane == 0) {
      int flat = 16383 - (int)(g & 0xFFFFFFFFull);
      int cc = flat / MAXDET;
      float sc = __uint_as_float((uint32_t)(g >> 32));
      fin_s[b * MAXDET + step] = sc;
      fin_c[b * MAXDET + step] = (float)(cc + 1);
      float4 bx = all_b[(size_t)b * NCC * MAXDET + flat];
      ((float4*)fin_b)[b * MAXDET + step] = bx;
      if (sc > -1.0f) cnt++;
    }
  }
  if (lane == 0) numo[b] = (float)cnt;
}

extern "C" void kernel_launch(void* const* d_in, const int* in_sizes, int n_in,
                              void* d_out, int out_size, void* d_ws, size_t ws_size,
                              hipStream_t stream) {
  const float* raw_boxes   = (const float*)d_in[0];
  const float* raw_scores  = (const float*)d_in[1];
  const float* anchors     = (const float*)d_in[2];
  const float* image_shape = (const float*)d_in[3];

  char* p = (char*)d_ws;
  auto alloc = [&](size_t bytes) {
    char* r = p;
    p += (bytes + 255) & ~(size_t)255;
    return r;
  };
  float2* stats = (float2*)alloc((size_t)B_SZ * K_ANCH * sizeof(float2));       // 512 KB
  ull*    bmask = (ull*)   alloc((size_t)B_SZ * NCC * NBW * sizeof(ull));       // 720 KB
  float*  all_s = (float*) alloc((size_t)B_SZ * NCC * MAXDET * sizeof(float));  // 288 KB
  float4* all_b = (float4*)alloc((size_t)B_SZ * NCC * MAXDET * sizeof(float4)); // 1.15 MB

  kT_softmax<<<B_SZ * 128, 1024, 0, stream>>>(raw_scores, stats, bmask);
  kN_nms<<<B_SZ * NCC, 256, 0, stream>>>(raw_boxes, raw_scores, anchors, image_shape,
                                         stats, bmask, all_s, all_b);
  k3_final<<<B_SZ, 256, 0, stream>>>(all_s, all_b, (float*)d_out);
}